// Round 6
// baseline (3362.515 us; speedup 1.0000x reference)
//
#include <hip/hip_runtime.h>
#include <hip/hip_bf16.h>
#include <stdint.h>

// ---------------------------------------------------------------------------
// BiLSTM classifier: V=50000 E=100 H=128 B=128 T=1024 C=2. f32 I/O.
// Round 6 = round 5 (passed, 2890 us) + lstm issue-cuts:
//   * xpc in lane-contiguous layout -> 2 dwordx4 loads/step (was 16 scalar)
//   * gate math: 5 exp + 2 rcp per element via shared denominators, no clamps
//   * pointer-increment OUT indexing
// Structure: padw, cvt6, per chunk (TC=128 x 8): proj (bf16 MFMA) -> lstm
// (16 persistent WGs, w_hh in VGPRs, h bf16 LDS double-buffer, c f32 regs),
// fc head. Workspace identical to round 5 (102.3 MB, proven).
// ---------------------------------------------------------------------------

typedef unsigned short u16;
typedef short bf16x8 __attribute__((ext_vector_type(8)));
typedef unsigned short ushort8v __attribute__((ext_vector_type(8)));
typedef float f32x4 __attribute__((ext_vector_type(4)));

#define NB 128
#define NT 1024
#define NH 128
#define NM (NB * NT)   // 131072
#define TC 128         // chunk length (steps)
#define NCHUNK (NT / TC)

#define L2E  1.44269504088896f
#define L2E2 2.88539008177793f

__device__ __forceinline__ u16 f2bf(float f) {
  union { float f; unsigned int i; } v; v.f = f;
  unsigned int i = v.i;
  return (u16)((i + 0x7FFFu + ((i >> 16) & 1u)) >> 16);  // RNE
}
__device__ __forceinline__ float bf2f(u16 u) {
  union { unsigned int i; float f; } v; v.i = ((unsigned int)u) << 16; return v.f;
}

#if __has_builtin(__builtin_amdgcn_exp2f)
__device__ __forceinline__ float fast_exp2(float x) { return __builtin_amdgcn_exp2f(x); }
#else
__device__ __forceinline__ float fast_exp2(float x) { return exp2f(x); }
#endif
#if __has_builtin(__builtin_amdgcn_rcpf)
__device__ __forceinline__ float fast_rcp(float x) { return __builtin_amdgcn_rcpf(x); }
#else
__device__ __forceinline__ float fast_rcp(float x) { return 1.0f / x; }
#endif

// ---------------------------------------------------------------------------
// pad w_ih_l0 f32 [512,100] -> bf16 [2][512][128] (zeros in cols 100:128)
__global__ void padw_kernel(const float* __restrict__ w0, const float* __restrict__ w1,
                            u16* __restrict__ out) {
  int idx = blockIdx.x * 256 + threadIdx.x;  // 131072
  int d = idx >> 16;
  int n = (idx >> 7) & 511;
  int k = idx & 127;
  const float* w = d ? w1 : w0;
  out[idx] = (k < 100) ? f2bf(w[n * 100 + k]) : (u16)0;
}

// fused f32->bf16 convert for 6 weight arrays (grid.y selects array)
__global__ void cvt6_kernel(const float* s0, const float* s1, const float* s2,
                            const float* s3, const float* s4, const float* s5,
                            u16* d0, u16* d1, u16* d2, u16* d3, u16* d4, u16* d5,
                            int n0, int n1, int n2, int n3, int n4, int n5) {
  int y = blockIdx.y;
  const float* s; u16* d; int n;
  switch (y) {
    case 0: s = s0; d = d0; n = n0; break;
    case 1: s = s1; d = d1; n = n1; break;
    case 2: s = s2; d = d2; n = n2; break;
    case 3: s = s3; d = d3; n = n3; break;
    case 4: s = s4; d = d4; n = n4; break;
    default: s = s5; d = d5; n = n5; break;
  }
  int i = blockIdx.x * 256 + threadIdx.x;
  if (i < n) d[i] = f2bf(s[i]);
}

// ---------------------------------------------------------------------------
// projection GEMM for one chunk. Output xpc layout is LANE-CONTIGUOUS for the
// lstm consumer: xpc[dir][wg(8)][sl(TC)][wv(8)][lane(64)][16 vals bf16],
// vals idx = r*4+gi for the lstm lane (q,l15): value of gate col
// gi*128+16*wv+l15, batch row wg*16+q*4+r, step sl. One lstm lane's 16 vals
// are 32 contiguous bytes -> 2 dwordx4 loads.
template <int K, bool GATHER>
__global__ __launch_bounds__(256) void proj_chunk(
    const float* __restrict__ Aemb, const u16* __restrict__ Ah,
    const int* __restrict__ X,
    const u16* __restrict__ W0, const u16* __restrict__ W1,   // [512][K] bf16
    const float* __restrict__ bih0, const float* __restrict__ bhh0,
    const float* __restrict__ bih1, const float* __restrict__ bhh1,
    u16* __restrict__ XPC, int c)
{
  constexpr int BK = 64;
  constexpr int LDA = 72;  // row stride 144 B (16B multiple)
  __shared__ __align__(16) u16 As[128 * LDA];
  __shared__ __align__(16) u16 Bs[128 * LDA];
  __shared__ int toks[128];

  const int b = blockIdx.x;
  const int nt0 = blockIdx.y * 128;
  const int dir = blockIdx.z;
  const u16* W = dir ? W1 : W0;

  const int tid = threadIdx.x;
  const int lane = tid & 63, wv = tid >> 6;
  const int wr = wv >> 1, wc = wv & 1;
  const int l15 = lane & 15, q = lane >> 4;

  if (GATHER) {
    if (tid < 128) {
      int t = dir ? (NT - 1 - c * TC - tid) : (c * TC + tid);
      toks[tid] = X[b * NT + t];
    }
  }

  f32x4 acc[4][4];
#pragma unroll
  for (int a = 0; a < 4; a++)
#pragma unroll
    for (int bb = 0; bb < 4; bb++)
      acc[a][bb] = (f32x4){0.f, 0.f, 0.f, 0.f};

  const int srow = tid >> 3;        // 0..31
  const int sseg = (tid & 7) * 8;   // 0..56

  for (int k0 = 0; k0 < K; k0 += BK) {
    __syncthreads();   // also covers toks on first iteration
#pragma unroll
    for (int p = 0; p < 4; p++) {
      int row = srow + p * 32;
      if (GATHER) {
        int tok = toks[row];
        const float* er = Aemb + (size_t)tok * 100;
        int kb = k0 + sseg;
        union { ushort8v v; u16 e[8]; } tu;
        if (kb + 8 <= 100) {
          f32x4 a0 = *(const f32x4*)&er[kb];      // 16B-aligned: 400*tok + 4*kb
          f32x4 a1 = *(const f32x4*)&er[kb + 4];
#pragma unroll
          for (int j = 0; j < 4; j++) { tu.e[j] = f2bf(a0[j]); tu.e[4 + j] = f2bf(a1[j]); }
        } else {
#pragma unroll
          for (int j = 0; j < 8; j++) tu.e[j] = (kb + j < 100) ? f2bf(er[kb + j]) : (u16)0;
        }
        *(ushort8v*)&As[row * LDA + sseg] = tu.v;
      } else {
        int t = dir ? (NT - 1 - c * TC - row) : (c * TC + row);
        const u16* srcA = Ah + (size_t)(b * NT + t) * K + k0 + sseg;
        *(ushort8v*)&As[row * LDA + sseg] = *(const ushort8v*)srcA;
      }
      const u16* srcB = W + (size_t)(nt0 + row) * K + k0 + sseg;
      *(ushort8v*)&Bs[row * LDA + sseg] = *(const ushort8v*)srcB;
    }
    __syncthreads();
#pragma unroll
    for (int kk = 0; kk < BK; kk += 32) {
      bf16x8 af[4], bfr[4];
#pragma unroll
      for (int mt = 0; mt < 4; mt++)
        af[mt] = *(const bf16x8*)&As[(wr * 64 + mt * 16 + l15) * LDA + kk + q * 8];
#pragma unroll
      for (int nt = 0; nt < 4; nt++)
        bfr[nt] = *(const bf16x8*)&Bs[(wc * 64 + nt * 16 + l15) * LDA + kk + q * 8];
#pragma unroll
      for (int mt = 0; mt < 4; mt++)
#pragma unroll
        for (int nt = 0; nt < 4; nt++)
          acc[mt][nt] = __builtin_amdgcn_mfma_f32_16x16x32_bf16(af[mt], bfr[nt], acc[mt][nt], 0, 0, 0);
    }
  }

  // epilogue: scatter into lane-contiguous lstm layout
  const float* bih = dir ? bih1 : bih0;
  const float* bhh = dir ? bhh1 : bhh0;
  const int gi = blockIdx.y;              // n>>7 == blockIdx.y (nt0 = y*128)
  const int qt = (b >> 2) & 3, rt = b & 3;
  u16* xo = XPC + ((size_t)(dir * 8 + (b >> 4)) * TC) * 8192;  // per (dir,wg): TC*8*64*16
#pragma unroll
  for (int nt = 0; nt < 4; nt++) {
    int n = nt0 + wc * 64 + nt * 16 + l15;
    float bias = bih[n] + bhh[n];
    int wvt = wc * 4 + nt;
#pragma unroll
    for (int mt = 0; mt < 4; mt++) {
#pragma unroll
      for (int r = 0; r < 4; r++) {
        int m = wr * 64 + mt * 16 + q * 4 + r;  // sl
        xo[((m * 8 + wvt) * 64 + qt * 16 + l15) * 16 + rt * 4 + gi] =
            f2bf(acc[mt][nt][r] + bias);
      }
    }
  }
}

// ---------------------------------------------------------------------------
// recurrent LSTM, one chunk of TC steps. grid (8 batch-chunks, 2 dirs),
// block 512 (8 waves). Wave wv owns within-gate cols [16wv,16wv+16): i/f/g/o
// for one h-element land in one lane; c f32 in VGPRs; h bf16 LDS dbuf;
// w_hh resident bf16 VGPRs; xp via 2 dwordx4/step, 1-step register prefetch.
// Gate math: 5 exp2 + 2 rcp per element (shared denominators), no clamps
// (|preact| << 44 so exp2 cannot overflow).
template <int LAYER>
__global__ __launch_bounds__(512) void lstm_chunk(
    const u16* __restrict__ XPC,         // lane-contiguous layout (see proj)
    const u16* __restrict__ WHH0, const u16* __restrict__ WHH1,  // [512][128] bf16
    u16* __restrict__ OUT,               // layer0: h1cat bf16 [NM][256]
    float* __restrict__ FINALS,          // layer1: [128][256] f32
    u16* __restrict__ HS, float* __restrict__ CS,  // [2][128][128] state
    int c)
{
  const int wg = blockIdx.x, dir = blockIdx.y;
  const int tid = threadIdx.x;
  const int lane = tid & 63, wv = tid >> 6;
  const int l15 = lane & 15, q = lane >> 4;
  const int hc = 16 * wv + l15;

  const u16* Wp = dir ? WHH1 : WHH0;
  bf16x8 wf[4][4];
#pragma unroll
  for (int gi = 0; gi < 4; gi++)
#pragma unroll
    for (int kt = 0; kt < 4; kt++)
      wf[gi][kt] = *(const bf16x8*)&Wp[(gi * 128 + hc) * 128 + kt * 32 + q * 8];

  __shared__ __align__(16) u16 hb[2][16 * 136];  // row stride 136

  float cst[4];
  if (c == 0) {
    for (int i = tid; i < 16 * 136; i += 512) hb[0][i] = 0;
#pragma unroll
    for (int r = 0; r < 4; r++) cst[r] = 0.f;
  } else {
#pragma unroll
    for (int r = 0; r < 4; r++) {
      int row = q * 4 + r;
      int g = (dir * 128 + wg * 16 + row) * 128 + hc;
      hb[0][row * 136 + hc] = HS[g];
      cst[r] = CS[g];
    }
  }

  // xp base for this lane; per-step stride 8192 u16 (16 KB)
  const u16* xbase = XPC + ((((size_t)(dir * 8 + wg) * TC) * 8 + wv) * 64 + lane) * 16;

  union XU { ushort8v v[2]; u16 e[16]; };
  XU xr, xn;
  xr.v[0] = *(const ushort8v*)(xbase);
  xr.v[1] = *(const ushort8v*)(xbase + 8);

  // per-r OUT pointers (layer 0), stepped by +/-256 per step
  const int t0 = dir ? (NT - 1 - c * TC) : (c * TC);
  const int tstep = dir ? -256 : 256;
  u16* optr[4];
  if (LAYER == 0) {
#pragma unroll
    for (int r = 0; r < 4; r++)
      optr[r] = OUT + ((size_t)(wg * 16 + q * 4 + r) * NT + t0) * 256 + dir * 128 + hc;
  }

  __syncthreads();

  int p = 0;
  for (int sl = 0; sl < TC; sl++) {
    bf16x8 ah[4];
#pragma unroll
    for (int kt = 0; kt < 4; kt++)
      ah[kt] = *(const bf16x8*)&hb[p][l15 * 136 + kt * 32 + q * 8];

    // prefetch next step's xp (clamped index: harmless re-read at last step)
    {
      const u16* nb = xbase + (size_t)((sl + 1 < TC) ? sl + 1 : sl) * 8192;
      xn.v[0] = *(const ushort8v*)(nb);
      xn.v[1] = *(const ushort8v*)(nb + 8);
    }

    f32x4 acc[4];
#pragma unroll
    for (int gi = 0; gi < 4; gi++)
#pragma unroll
      for (int r = 0; r < 4; r++)
        acc[gi][r] = bf2f(xr.e[r * 4 + gi]);
#pragma unroll
    for (int gi = 0; gi < 4; gi++)
#pragma unroll
      for (int kt = 0; kt < 4; kt++)
        acc[gi] = __builtin_amdgcn_mfma_f32_16x16x32_bf16(ah[kt], wf[gi][kt], acc[gi], 0, 0, 0);

#pragma unroll
    for (int r = 0; r < 4; r++) {
      float ei = fast_exp2(L2E * acc[0][r]);
      float ef = fast_exp2(L2E * acc[1][r]);
      float eg = fast_exp2(L2E2 * acc[2][r]);
      float eo = fast_exp2(L2E * acc[3][r]);
      float A = 1.f + ef, B = 1.f + ei, Cg = 1.f + eg;
      float BC = B * Cg;
      // c = sigma(f)*c + sigma(i)*tanh(g), one rcp via common denominator
      float num = cst[r] * ef * BC + ei * (eg - 1.f) * A;
      float cn = num * fast_rcp(A * BC);
      cst[r] = cn;
      float ec = fast_exp2(L2E2 * cn);
      float hv = eo * (ec - 1.f) * fast_rcp((1.f + eo) * (1.f + ec));
      u16 hbv = f2bf(hv);
      int row = q * 4 + r;
      hb[p ^ 1][row * 136 + hc] = hbv;
      if (LAYER == 0) {
        *optr[r] = hbv;
        optr[r] += tstep;
      }
      if (sl == TC - 1) {
        int g = (dir * 128 + wg * 16 + row) * 128 + hc;
        HS[g] = hbv;
        CS[g] = cst[r];
        if (LAYER == 1 && c == NCHUNK - 1)
          FINALS[(wg * 16 + row) * 256 + dir * 128 + hc] = hv;
      }
    }
    __syncthreads();
    p ^= 1;
    xr.v[0] = xn.v[0];
    xr.v[1] = xn.v[1];
  }
}

// ---------------------------------------------------------------------------
// fc: out[b][c] = finals[b][:] . fc_w[c][:] + fc_b[c]  (all f32)
__global__ void fc_kernel(const float* __restrict__ finals, const float* __restrict__ fcw,
                          const float* __restrict__ fcb, float* __restrict__ out) {
  int tid = threadIdx.x;  // 256 = 128 b x 2 c
  int b = tid >> 1, cc = tid & 1;
  float s = fcb[cc];
  for (int k = 0; k < 256; k++) s += finals[b * 256 + k] * fcw[cc * 256 + k];
  out[b * 2 + cc] = s;
}

// ---------------------------------------------------------------------------
extern "C" void kernel_launch(void* const* d_in, const int* in_sizes, int n_in,
                              void* d_out, int out_size, void* d_ws, size_t ws_size,
                              hipStream_t stream) {
  const int*   x        = (const int*)d_in[0];
  const float* emb      = (const float*)d_in[1];
  const float* w_ih_l0  = (const float*)d_in[2];
  const float* w_hh_l0  = (const float*)d_in[3];
  const float* b_ih_l0  = (const float*)d_in[4];
  const float* b_hh_l0  = (const float*)d_in[5];
  const float* w_ih_l0r = (const float*)d_in[6];
  const float* w_hh_l0r = (const float*)d_in[7];
  const float* b_ih_l0r = (const float*)d_in[8];
  const float* b_hh_l0r = (const float*)d_in[9];
  const float* w_ih_l1  = (const float*)d_in[10];
  const float* w_hh_l1  = (const float*)d_in[11];
  const float* b_ih_l1  = (const float*)d_in[12];
  const float* b_hh_l1  = (const float*)d_in[13];
  const float* w_ih_l1r = (const float*)d_in[14];
  const float* w_hh_l1r = (const float*)d_in[15];
  const float* b_ih_l1r = (const float*)d_in[16];
  const float* b_hh_l1r = (const float*)d_in[17];
  const float* fc_w     = (const float*)d_in[18];
  const float* fc_b     = (const float*)d_in[19];
  float* out = (float*)d_out;

  // workspace layout — total 102,301,696 B (proven available in r5)
  char* ws = (char*)d_ws;
  size_t off = 0;
  u16*   h1cat = (u16*)(ws + off);   off += 67108864;  // [NM][256] bf16
  u16*   xpc   = (u16*)(ws + off);   off += 33554432;  // lane-contig layout bf16
  u16*   w0pad = (u16*)(ws + off);   off += 262144;    // [2][512][128] bf16
  u16*   wih1b = (u16*)(ws + off);   off += 524288;    // [2][512][256] bf16
  u16*   whhb  = (u16*)(ws + off);   off += 524288;    // [4][512][128] bf16
  u16*   hs    = (u16*)(ws + off);   off += 65536;     // [2][128][128] bf16
  float* cs    = (float*)(ws + off); off += 131072;    // [2][128][128] f32
  float* fin   = (float*)(ws + off); off += 131072;    // [128][256] f32
  if (ws_size < off) return;  // constant across calls -> same work every call

  hipLaunchKernelGGL(padw_kernel, dim3(512), dim3(256), 0, stream,
                     w_ih_l0, w_ih_l0r, w0pad);
  hipLaunchKernelGGL(cvt6_kernel, dim3(512, 6), dim3(256), 0, stream,
                     w_hh_l0, w_hh_l0r, w_hh_l1, w_hh_l1r, w_ih_l1, w_ih_l1r,
                     whhb, whhb + 65536, whhb + 131072, whhb + 196608,
                     wih1b, wih1b + 131072,
                     65536, 65536, 65536, 65536, 131072, 131072);

  for (int c = 0; c < NCHUNK; c++) {
    hipLaunchKernelGGL((proj_chunk<128, true>), dim3(128, 4, 2), dim3(256), 0, stream,
                       emb, (const u16*)nullptr, x, w0pad, w0pad + 65536,
                       b_ih_l0, b_hh_l0, b_ih_l0r, b_hh_l0r, xpc, c);
    hipLaunchKernelGGL((lstm_chunk<0>), dim3(8, 2), dim3(512), 0, stream,
                       xpc, whhb, whhb + 65536, h1cat, fin, hs, cs, c);
  }
  for (int c = 0; c < NCHUNK; c++) {
    hipLaunchKernelGGL((proj_chunk<256, false>), dim3(128, 4, 2), dim3(256), 0, stream,
                       (const float*)nullptr, h1cat, (const int*)nullptr,
                       wih1b, wih1b + 131072,
                       b_ih_l1, b_hh_l1, b_ih_l1r, b_hh_l1r, xpc, c);
    hipLaunchKernelGGL((lstm_chunk<1>), dim3(8, 2), dim3(512), 0, stream,
                       xpc, whhb + 131072, whhb + 196608, h1cat, fin, hs, cs, c);
  }
  hipLaunchKernelGGL(fc_kernel, dim3(1), dim3(256), 0, stream, fin, fc_w, fc_b, out);
}

// Round 7
// 2574.655 us; speedup vs baseline: 1.3060x; 1.3060x over previous
//
#include <hip/hip_runtime.h>
#include <hip/hip_bf16.h>
#include <stdint.h>

// ---------------------------------------------------------------------------
// BiLSTM classifier: V=50000 E=100 H=128 B=128 T=1024 C=2. f32 I/O.
// Round 7 = r5 proj (natural xpc layout, coalesced stores, proven 24us)
//         + r6 lstm gate math (5 exp + 2 rcp, no clamps) + pointer-inc OUT
//         + r5 xp scalar-load pattern (isolates load cost vs math cost).
// ---------------------------------------------------------------------------

typedef unsigned short u16;
typedef short bf16x8 __attribute__((ext_vector_type(8)));
typedef unsigned short ushort8v __attribute__((ext_vector_type(8)));
typedef float f32x4 __attribute__((ext_vector_type(4)));

#define NB 128
#define NT 1024
#define NH 128
#define NM (NB * NT)   // 131072
#define TC 128         // chunk length (steps)
#define NCHUNK (NT / TC)

#define L2E  1.44269504088896f
#define L2E2 2.88539008177793f

__device__ __forceinline__ u16 f2bf(float f) {
  union { float f; unsigned int i; } v; v.f = f;
  unsigned int i = v.i;
  return (u16)((i + 0x7FFFu + ((i >> 16) & 1u)) >> 16);  // RNE
}
__device__ __forceinline__ float bf2f(u16 u) {
  union { unsigned int i; float f; } v; v.i = ((unsigned int)u) << 16; return v.f;
}

#if __has_builtin(__builtin_amdgcn_exp2f)
__device__ __forceinline__ float fast_exp2(float x) { return __builtin_amdgcn_exp2f(x); }
#else
__device__ __forceinline__ float fast_exp2(float x) { return exp2f(x); }
#endif
#if __has_builtin(__builtin_amdgcn_rcpf)
__device__ __forceinline__ float fast_rcp(float x) { return __builtin_amdgcn_rcpf(x); }
#else
__device__ __forceinline__ float fast_rcp(float x) { return 1.0f / x; }
#endif

// ---------------------------------------------------------------------------
// pad w_ih_l0 f32 [512,100] -> bf16 [2][512][128] (zeros in cols 100:128)
__global__ void padw_kernel(const float* __restrict__ w0, const float* __restrict__ w1,
                            u16* __restrict__ out) {
  int idx = blockIdx.x * 256 + threadIdx.x;  // 131072
  int d = idx >> 16;
  int n = (idx >> 7) & 511;
  int k = idx & 127;
  const float* w = d ? w1 : w0;
  out[idx] = (k < 100) ? f2bf(w[n * 100 + k]) : (u16)0;
}

// fused f32->bf16 convert for 6 weight arrays (grid.y selects array)
__global__ void cvt6_kernel(const float* s0, const float* s1, const float* s2,
                            const float* s3, const float* s4, const float* s5,
                            u16* d0, u16* d1, u16* d2, u16* d3, u16* d4, u16* d5,
                            int n0, int n1, int n2, int n3, int n4, int n5) {
  int y = blockIdx.y;
  const float* s; u16* d; int n;
  switch (y) {
    case 0: s = s0; d = d0; n = n0; break;
    case 1: s = s1; d = d1; n = n1; break;
    case 2: s = s2; d = d2; n = n2; break;
    case 3: s = s3; d = d3; n = n3; break;
    case 4: s = s4; d = d4; n = n4; break;
    default: s = s5; d = d5; n = n5; break;
  }
  int i = blockIdx.x * 256 + threadIdx.x;
  if (i < n) d[i] = f2bf(s[i]);
}

// ---------------------------------------------------------------------------
// projection GEMM for one chunk (r5 version, natural layout): xpc[dir][b][tl][n]
// (bf16) = A[b, t(dir,c,tl), :] . W[n,:] + b_ih[n] + b_hh[n]
// GATHER: layer 0 — A-rows gathered from emb (f32, cvt inline).
// else:   layer 1 — A = h1cat bf16 [NM][256].
// grid (128 b, 4 ntile, 2 dir), block 256 (4 waves, 2x2 of 64x64).
template <int K, bool GATHER>
__global__ __launch_bounds__(256) void proj_chunk(
    const float* __restrict__ Aemb, const u16* __restrict__ Ah,
    const int* __restrict__ X,
    const u16* __restrict__ W0, const u16* __restrict__ W1,   // [512][K] bf16
    const float* __restrict__ bih0, const float* __restrict__ bhh0,
    const float* __restrict__ bih1, const float* __restrict__ bhh1,
    u16* __restrict__ XPC, int c)
{
  constexpr int BK = 64;
  constexpr int LDA = 72;  // row stride 144 B (16B multiple)
  __shared__ __align__(16) u16 As[128 * LDA];
  __shared__ __align__(16) u16 Bs[128 * LDA];
  __shared__ int toks[128];

  const int b = blockIdx.x;
  const int nt0 = blockIdx.y * 128;
  const int dir = blockIdx.z;
  const u16* W = dir ? W1 : W0;

  const int tid = threadIdx.x;
  const int lane = tid & 63, wv = tid >> 6;
  const int wr = wv >> 1, wc = wv & 1;
  const int l15 = lane & 15, q = lane >> 4;

  if (GATHER) {
    if (tid < 128) {
      int t = dir ? (NT - 1 - c * TC - tid) : (c * TC + tid);
      toks[tid] = X[b * NT + t];
    }
  }

  f32x4 acc[4][4];
#pragma unroll
  for (int a = 0; a < 4; a++)
#pragma unroll
    for (int bb = 0; bb < 4; bb++)
      acc[a][bb] = (f32x4){0.f, 0.f, 0.f, 0.f};

  const int srow = tid >> 3;        // 0..31
  const int sseg = (tid & 7) * 8;   // 0..56

  for (int k0 = 0; k0 < K; k0 += BK) {
    __syncthreads();   // also covers toks on first iteration
#pragma unroll
    for (int p = 0; p < 4; p++) {
      int row = srow + p * 32;
      if (GATHER) {
        int tok = toks[row];
        const float* er = Aemb + (size_t)tok * 100;
        int kb = k0 + sseg;
        union { ushort8v v; u16 e[8]; } tu;
        if (kb + 8 <= 100) {
          f32x4 a0 = *(const f32x4*)&er[kb];      // 16B-aligned: 400*tok + 4*kb
          f32x4 a1 = *(const f32x4*)&er[kb + 4];
#pragma unroll
          for (int j = 0; j < 4; j++) { tu.e[j] = f2bf(a0[j]); tu.e[4 + j] = f2bf(a1[j]); }
        } else {
#pragma unroll
          for (int j = 0; j < 8; j++) tu.e[j] = (kb + j < 100) ? f2bf(er[kb + j]) : (u16)0;
        }
        *(ushort8v*)&As[row * LDA + sseg] = tu.v;
      } else {
        int t = dir ? (NT - 1 - c * TC - row) : (c * TC + row);
        const u16* srcA = Ah + (size_t)(b * NT + t) * K + k0 + sseg;
        *(ushort8v*)&As[row * LDA + sseg] = *(const ushort8v*)srcA;
      }
      const u16* srcB = W + (size_t)(nt0 + row) * K + k0 + sseg;
      *(ushort8v*)&Bs[row * LDA + sseg] = *(const ushort8v*)srcB;
    }
    __syncthreads();
#pragma unroll
    for (int kk = 0; kk < BK; kk += 32) {
      bf16x8 af[4], bfr[4];
#pragma unroll
      for (int mt = 0; mt < 4; mt++)
        af[mt] = *(const bf16x8*)&As[(wr * 64 + mt * 16 + l15) * LDA + kk + q * 8];
#pragma unroll
      for (int nt = 0; nt < 4; nt++)
        bfr[nt] = *(const bf16x8*)&Bs[(wc * 64 + nt * 16 + l15) * LDA + kk + q * 8];
#pragma unroll
      for (int mt = 0; mt < 4; mt++)
#pragma unroll
        for (int nt = 0; nt < 4; nt++)
          acc[mt][nt] = __builtin_amdgcn_mfma_f32_16x16x32_bf16(af[mt], bfr[nt], acc[mt][nt], 0, 0, 0);
    }
  }

  const float* bih = dir ? bih1 : bih0;
  const float* bhh = dir ? bhh1 : bhh0;
  u16* xo = XPC + ((size_t)(dir * 128 + b) * TC) * 512;
#pragma unroll
  for (int nt = 0; nt < 4; nt++) {
    int n = nt0 + wc * 64 + nt * 16 + l15;
    float bias = bih[n] + bhh[n];
#pragma unroll
    for (int mt = 0; mt < 4; mt++) {
      int rbase = wr * 64 + mt * 16 + q * 4;   // = tl (step-local index)
#pragma unroll
      for (int r = 0; r < 4; r++)
        xo[(size_t)(rbase + r) * 512 + n] = f2bf(acc[mt][nt][r] + bias);
    }
  }
}

// ---------------------------------------------------------------------------
// recurrent LSTM, one chunk of TC steps. grid (8 batch-chunks, 2 dirs),
// block 512 (8 waves). Wave wv owns within-gate cols [16wv,16wv+16): i/f/g/o
// for one h-element land in one lane; c f32 in VGPRs; h bf16 LDS dbuf;
// w_hh resident bf16 VGPRs; xp from r5 natural layout (16 scalar bf16 loads
// per lane per step, 1-step register prefetch).
// Gate math: 5 exp2 + 2 rcp per element (shared denominators), no clamps.
template <int LAYER>
__global__ __launch_bounds__(512) void lstm_chunk(
    const u16* __restrict__ XPC,         // [2][128][TC][512] bf16 (natural)
    const u16* __restrict__ WHH0, const u16* __restrict__ WHH1,  // [512][128] bf16
    u16* __restrict__ OUT,               // layer0: h1cat bf16 [NM][256]
    float* __restrict__ FINALS,          // layer1: [128][256] f32
    u16* __restrict__ HS, float* __restrict__ CS,  // [2][128][128] state
    int c)
{
  const int wg = blockIdx.x, dir = blockIdx.y;
  const int tid = threadIdx.x;
  const int lane = tid & 63, wv = tid >> 6;
  const int l15 = lane & 15, q = lane >> 4;
  const int hc = 16 * wv + l15;

  const u16* Wp = dir ? WHH1 : WHH0;
  bf16x8 wf[4][4];
#pragma unroll
  for (int gi = 0; gi < 4; gi++)
#pragma unroll
    for (int kt = 0; kt < 4; kt++)
      wf[gi][kt] = *(const bf16x8*)&Wp[(gi * 128 + hc) * 128 + kt * 32 + q * 8];

  __shared__ __align__(16) u16 hb[2][16 * 136];  // row stride 136

  float cst[4];
  if (c == 0) {
    for (int i = tid; i < 16 * 136; i += 512) hb[0][i] = 0;
#pragma unroll
    for (int r = 0; r < 4; r++) cst[r] = 0.f;
  } else {
#pragma unroll
    for (int r = 0; r < 4; r++) {
      int row = q * 4 + r;
      int g = (dir * 128 + wg * 16 + row) * 128 + hc;
      hb[0][row * 136 + hc] = HS[g];
      cst[r] = CS[g];
    }
  }

  // xp pointers (r5 natural layout): lane reads 16 scalars per step
  const u16* xpp = XPC + ((size_t)(dir * 128 + wg * 16) * TC) * 512;
  float xpv[16];
#pragma unroll
  for (int gi = 0; gi < 4; gi++)
#pragma unroll
    for (int r = 0; r < 4; r++)
      xpv[gi * 4 + r] = bf2f(xpp[((size_t)(q * 4 + r) * TC) * 512 + gi * 128 + hc]);

  // per-r OUT pointers (layer 0), stepped by +/-256 per step
  const int t0 = dir ? (NT - 1 - c * TC) : (c * TC);
  const int tstep = dir ? -256 : 256;
  u16* optr[4];
  if (LAYER == 0) {
#pragma unroll
    for (int r = 0; r < 4; r++)
      optr[r] = OUT + ((size_t)(wg * 16 + q * 4 + r) * NT + t0) * 256 + dir * 128 + hc;
  }

  __syncthreads();

  int p = 0;
  for (int sl = 0; sl < TC; sl++) {
    bf16x8 ah[4];
#pragma unroll
    for (int kt = 0; kt < 4; kt++)
      ah[kt] = *(const bf16x8*)&hb[p][l15 * 136 + kt * 32 + q * 8];

    // prefetch next step's xp (clamped index: harmless re-read at last step)
    const int sln = (sl + 1 < TC) ? sl + 1 : sl;
    float xnv[16];
#pragma unroll
    for (int gi = 0; gi < 4; gi++)
#pragma unroll
      for (int r = 0; r < 4; r++)
        xnv[gi * 4 + r] = bf2f(xpp[((size_t)(q * 4 + r) * TC + sln) * 512 + gi * 128 + hc]);

    f32x4 acc[4];
#pragma unroll
    for (int gi = 0; gi < 4; gi++)
#pragma unroll
      for (int r = 0; r < 4; r++)
        acc[gi][r] = xpv[gi * 4 + r];
#pragma unroll
    for (int gi = 0; gi < 4; gi++)
#pragma unroll
      for (int kt = 0; kt < 4; kt++)
        acc[gi] = __builtin_amdgcn_mfma_f32_16x16x32_bf16(ah[kt], wf[gi][kt], acc[gi], 0, 0, 0);

#pragma unroll
    for (int r = 0; r < 4; r++) {
      float ei = fast_exp2(L2E * acc[0][r]);
      float ef = fast_exp2(L2E * acc[1][r]);
      float eg = fast_exp2(L2E2 * acc[2][r]);
      float eo = fast_exp2(L2E * acc[3][r]);
      float A = 1.f + ef, B = 1.f + ei, Cg = 1.f + eg;
      float BC = B * Cg;
      // c = sigma(f)*c + sigma(i)*tanh(g), one rcp via common denominator
      float num = cst[r] * ef * BC + ei * (eg - 1.f) * A;
      float cn = num * fast_rcp(A * BC);
      cst[r] = cn;
      float ec = fast_exp2(L2E2 * cn);
      float hv = eo * (ec - 1.f) * fast_rcp((1.f + eo) * (1.f + ec));
      u16 hbv = f2bf(hv);
      int row = q * 4 + r;
      hb[p ^ 1][row * 136 + hc] = hbv;
      if (LAYER == 0) {
        *optr[r] = hbv;
        optr[r] += tstep;
      }
      if (sl == TC - 1) {
        int g = (dir * 128 + wg * 16 + row) * 128 + hc;
        HS[g] = hbv;
        CS[g] = cst[r];
        if (LAYER == 1 && c == NCHUNK - 1)
          FINALS[(wg * 16 + row) * 256 + dir * 128 + hc] = hv;
      }
    }
    __syncthreads();
    p ^= 1;
#pragma unroll
    for (int i = 0; i < 16; i++) xpv[i] = xnv[i];
  }
}

// ---------------------------------------------------------------------------
// fc: out[b][c] = finals[b][:] . fc_w[c][:] + fc_b[c]  (all f32)
__global__ void fc_kernel(const float* __restrict__ finals, const float* __restrict__ fcw,
                          const float* __restrict__ fcb, float* __restrict__ out) {
  int tid = threadIdx.x;  // 256 = 128 b x 2 c
  int b = tid >> 1, cc = tid & 1;
  float s = fcb[cc];
  for (int k = 0; k < 256; k++) s += finals[b * 256 + k] * fcw[cc * 256 + k];
  out[b * 2 + cc] = s;
}

// ---------------------------------------------------------------------------
extern "C" void kernel_launch(void* const* d_in, const int* in_sizes, int n_in,
                              void* d_out, int out_size, void* d_ws, size_t ws_size,
                              hipStream_t stream) {
  const int*   x        = (const int*)d_in[0];
  const float* emb      = (const float*)d_in[1];
  const float* w_ih_l0  = (const float*)d_in[2];
  const float* w_hh_l0  = (const float*)d_in[3];
  const float* b_ih_l0  = (const float*)d_in[4];
  const float* b_hh_l0  = (const float*)d_in[5];
  const float* w_ih_l0r = (const float*)d_in[6];
  const float* w_hh_l0r = (const float*)d_in[7];
  const float* b_ih_l0r = (const float*)d_in[8];
  const float* b_hh_l0r = (const float*)d_in[9];
  const float* w_ih_l1  = (const float*)d_in[10];
  const float* w_hh_l1  = (const float*)d_in[11];
  const float* b_ih_l1  = (const float*)d_in[12];
  const float* b_hh_l1  = (const float*)d_in[13];
  const float* w_ih_l1r = (const float*)d_in[14];
  const float* w_hh_l1r = (const float*)d_in[15];
  const float* b_ih_l1r = (const float*)d_in[16];
  const float* b_hh_l1r = (const float*)d_in[17];
  const float* fc_w     = (const float*)d_in[18];
  const float* fc_b     = (const float*)d_in[19];
  float* out = (float*)d_out;

  // workspace layout — total 102,301,696 B (proven available in r5/r6)
  char* ws = (char*)d_ws;
  size_t off = 0;
  u16*   h1cat = (u16*)(ws + off);   off += 67108864;  // [NM][256] bf16
  u16*   xpc   = (u16*)(ws + off);   off += 33554432;  // [2][128][TC][512] bf16
  u16*   w0pad = (u16*)(ws + off);   off += 262144;    // [2][512][128] bf16
  u16*   wih1b = (u16*)(ws + off);   off += 524288;    // [2][512][256] bf16
  u16*   whhb  = (u16*)(ws + off);   off += 524288;    // [4][512][128] bf16
  u16*   hs    = (u16*)(ws + off);   off += 65536;     // [2][128][128] bf16
  float* cs    = (float*)(ws + off); off += 131072;    // [2][128][128] f32
  float* fin   = (float*)(ws + off); off += 131072;    // [128][256] f32
  if (ws_size < off) return;  // constant across calls -> same work every call

  hipLaunchKernelGGL(padw_kernel, dim3(512), dim3(256), 0, stream,
                     w_ih_l0, w_ih_l0r, w0pad);
  hipLaunchKernelGGL(cvt6_kernel, dim3(512, 6), dim3(256), 0, stream,
                     w_hh_l0, w_hh_l0r, w_hh_l1, w_hh_l1r, w_ih_l1, w_ih_l1r,
                     whhb, whhb + 65536, whhb + 131072, whhb + 196608,
                     wih1b, wih1b + 131072,
                     65536, 65536, 65536, 65536, 131072, 131072);

  for (int c = 0; c < NCHUNK; c++) {
    hipLaunchKernelGGL((proj_chunk<128, true>), dim3(128, 4, 2), dim3(256), 0, stream,
                       emb, (const u16*)nullptr, x, w0pad, w0pad + 65536,
                       b_ih_l0, b_hh_l0, b_ih_l0r, b_hh_l0r, xpc, c);
    hipLaunchKernelGGL((lstm_chunk<0>), dim3(8, 2), dim3(512), 0, stream,
                       xpc, whhb, whhb + 65536, h1cat, fin, hs, cs, c);
  }
  for (int c = 0; c < NCHUNK; c++) {
    hipLaunchKernelGGL((proj_chunk<256, false>), dim3(128, 4, 2), dim3(256), 0, stream,
                       (const float*)nullptr, h1cat, (const int*)nullptr,
                       wih1b, wih1b + 131072,
                       b_ih_l1, b_hh_l1, b_ih_l1r, b_hh_l1r, xpc, c);
    hipLaunchKernelGGL((lstm_chunk<1>), dim3(8, 2), dim3(512), 0, stream,
                       xpc, whhb + 131072, whhb + 196608, h1cat, fin, hs, cs, c);
  }
  hipLaunchKernelGGL(fc_kernel, dim3(1), dim3(256), 0, stream, fin, fc_w, fc_b, out);
}

// Round 8
// 2223.126 us; speedup vs baseline: 1.5125x; 1.1581x over previous
//
#include <hip/hip_runtime.h>
#include <hip/hip_bf16.h>
#include <stdint.h>

// ---------------------------------------------------------------------------
// BiLSTM classifier: V=50000 E=100 H=128 B=128 T=1024 C=2. f32 I/O.
// Round 8 = r7 cores + FUSED launches: one kernel runs lstm chunk c (blocks
// 0..15, dispatched first) concurrently with proj chunk c+1 (blocks 16..1039)
// into a double-buffered xpc. Hides ~490us of proj wall time under lstm.
// Layers remain serial (bidirectionality: L1 chunk 0 needs all of L0).
// Workspace = 135,856,128 B (exact r2 footprint, proven to run).
// ---------------------------------------------------------------------------

typedef unsigned short u16;
typedef short bf16x8 __attribute__((ext_vector_type(8)));
typedef unsigned short ushort8v __attribute__((ext_vector_type(8)));
typedef float f32x4 __attribute__((ext_vector_type(4)));

#define NB 128
#define NT 1024
#define NH 128
#define NM (NB * NT)   // 131072
#define TC 128         // chunk length (steps)
#define NCHUNK (NT / TC)

#define L2E  1.44269504088896f
#define L2E2 2.88539008177793f

__device__ __forceinline__ u16 f2bf(float f) {
  union { float f; unsigned int i; } v; v.f = f;
  unsigned int i = v.i;
  return (u16)((i + 0x7FFFu + ((i >> 16) & 1u)) >> 16);  // RNE
}
__device__ __forceinline__ float bf2f(u16 u) {
  union { unsigned int i; float f; } v; v.i = ((unsigned int)u) << 16; return v.f;
}

#if __has_builtin(__builtin_amdgcn_exp2f)
__device__ __forceinline__ float fast_exp2(float x) { return __builtin_amdgcn_exp2f(x); }
#else
__device__ __forceinline__ float fast_exp2(float x) { return exp2f(x); }
#endif
#if __has_builtin(__builtin_amdgcn_rcpf)
__device__ __forceinline__ float fast_rcp(float x) { return __builtin_amdgcn_rcpf(x); }
#else
__device__ __forceinline__ float fast_rcp(float x) { return 1.0f / x; }
#endif

// ---------------------------------------------------------------------------
// pad w_ih_l0 f32 [512,100] -> bf16 [2][512][128] (zeros in cols 100:128)
__global__ void padw_kernel(const float* __restrict__ w0, const float* __restrict__ w1,
                            u16* __restrict__ out) {
  int idx = blockIdx.x * 256 + threadIdx.x;  // 131072
  int d = idx >> 16;
  int n = (idx >> 7) & 511;
  int k = idx & 127;
  const float* w = d ? w1 : w0;
  out[idx] = (k < 100) ? f2bf(w[n * 100 + k]) : (u16)0;
}

// fused f32->bf16 convert for 6 weight arrays (grid.y selects array)
__global__ void cvt6_kernel(const float* s0, const float* s1, const float* s2,
                            const float* s3, const float* s4, const float* s5,
                            u16* d0, u16* d1, u16* d2, u16* d3, u16* d4, u16* d5,
                            int n0, int n1, int n2, int n3, int n4, int n5) {
  int y = blockIdx.y;
  const float* s; u16* d; int n;
  switch (y) {
    case 0: s = s0; d = d0; n = n0; break;
    case 1: s = s1; d = d1; n = n1; break;
    case 2: s = s2; d = d2; n = n2; break;
    case 3: s = s3; d = d3; n = n3; break;
    case 4: s = s4; d = d4; n = n4; break;
    default: s = s5; d = d5; n = n5; break;
  }
  int i = blockIdx.x * 256 + threadIdx.x;
  if (i < n) d[i] = f2bf(s[i]);
}

// ---------------------------------------------------------------------------
// Fused kernel. Blocks 0..15: lstm chunk `lc` (if do_lstm). Blocks 16..1039:
// proj chunk `pc` (grid sized to 16 when do_proj==0).
// PK = proj K (128 w/ emb-gather for layer0, 256 from h1cat for layer1).
// LL = lstm layer (0 writes h1cat, 1 writes FINALS at last chunk).
template <int PK, int LL>
__global__ __launch_bounds__(512) void fused_chunk(
    int do_lstm, int lc, int pc,
    const float* __restrict__ Aemb, const u16* __restrict__ Ah,
    const int* __restrict__ X,
    const u16* __restrict__ W0, const u16* __restrict__ W1,   // [512][PK] bf16
    const float* __restrict__ bih0, const float* __restrict__ bhh0,
    const float* __restrict__ bih1, const float* __restrict__ bhh1,
    u16* __restrict__ xpc0, u16* __restrict__ xpc1,           // double buffer
    const u16* __restrict__ WHH0, const u16* __restrict__ WHH1,
    u16* __restrict__ OUT, float* __restrict__ FINALS,
    u16* __restrict__ HS, float* __restrict__ CS)
{
  // shared memory union: proj As(18432)+Bs(18432)+toks(512); lstm hb(8704)
  __shared__ __align__(16) unsigned char smem[37888];

  const int tid = threadIdx.x;
  const int lane = tid & 63, wv = tid >> 6;
  const int l15 = lane & 15, q = lane >> 4;

  if (blockIdx.x >= 16) {
    // ------------------------- proj part (8 waves, 64x32 wave tiles) -------
    constexpr int BK = 64;
    constexpr int LDA = 72;
    constexpr bool GATHER = (PK == 128);
    u16* As = (u16*)smem;
    u16* Bs = As + 128 * LDA;
    int* toks = (int*)(Bs + 128 * LDA);

    const int pb = blockIdx.x - 16;
    const int b = pb & 127;
    const int nt0 = ((pb >> 7) & 3) * 128;
    const int dir = pb >> 9;
    const u16* W = dir ? W1 : W0;
    u16* XPC = (pc & 1) ? xpc1 : xpc0;

    const int wr = wv >> 2, wc = wv & 3;   // 2 x 4 waves

    if (GATHER) {
      if (tid < 128) {
        int t = dir ? (NT - 1 - pc * TC - tid) : (pc * TC + tid);
        toks[tid] = X[b * NT + t];
      }
    }

    f32x4 acc[4][2];
#pragma unroll
    for (int a = 0; a < 4; a++)
#pragma unroll
      for (int bb = 0; bb < 2; bb++)
        acc[a][bb] = (f32x4){0.f, 0.f, 0.f, 0.f};

    const int srow = tid >> 3;        // 0..63
    const int sseg = (tid & 7) * 8;   // 0..56

    for (int k0 = 0; k0 < PK; k0 += BK) {
      __syncthreads();   // also covers toks on first iteration
#pragma unroll
      for (int p = 0; p < 2; p++) {
        int row = srow + p * 64;
        if (GATHER) {
          int tok = toks[row];
          const float* er = Aemb + (size_t)tok * 100;
          int kb = k0 + sseg;
          union { ushort8v v; u16 e[8]; } tu;
          if (kb + 8 <= 100) {
            f32x4 a0 = *(const f32x4*)&er[kb];
            f32x4 a1 = *(const f32x4*)&er[kb + 4];
#pragma unroll
            for (int j = 0; j < 4; j++) { tu.e[j] = f2bf(a0[j]); tu.e[4 + j] = f2bf(a1[j]); }
          } else {
#pragma unroll
            for (int j = 0; j < 8; j++) tu.e[j] = (kb + j < 100) ? f2bf(er[kb + j]) : (u16)0;
          }
          *(ushort8v*)&As[row * LDA + sseg] = tu.v;
        } else {
          int t = dir ? (NT - 1 - pc * TC - row) : (pc * TC + row);
          const u16* srcA = Ah + (size_t)(b * NT + t) * PK + k0 + sseg;
          *(ushort8v*)&As[row * LDA + sseg] = *(const ushort8v*)srcA;
        }
        const u16* srcB = W + (size_t)(nt0 + row) * PK + k0 + sseg;
        *(ushort8v*)&Bs[row * LDA + sseg] = *(const ushort8v*)srcB;
      }
      __syncthreads();
#pragma unroll
      for (int kk = 0; kk < BK; kk += 32) {
        bf16x8 af[4], bfr[2];
#pragma unroll
        for (int mt = 0; mt < 4; mt++)
          af[mt] = *(const bf16x8*)&As[(wr * 64 + mt * 16 + l15) * LDA + kk + q * 8];
#pragma unroll
        for (int nt = 0; nt < 2; nt++)
          bfr[nt] = *(const bf16x8*)&Bs[(wc * 32 + nt * 16 + l15) * LDA + kk + q * 8];
#pragma unroll
        for (int mt = 0; mt < 4; mt++)
#pragma unroll
          for (int nt = 0; nt < 2; nt++)
            acc[mt][nt] = __builtin_amdgcn_mfma_f32_16x16x32_bf16(af[mt], bfr[nt], acc[mt][nt], 0, 0, 0);
      }
    }

    const float* bih = dir ? bih1 : bih0;
    const float* bhh = dir ? bhh1 : bhh0;
    u16* xo = XPC + ((size_t)(dir * 128 + b) * TC) * 512;
#pragma unroll
    for (int nt = 0; nt < 2; nt++) {
      int n = nt0 + wc * 32 + nt * 16 + l15;
      float bias = bih[n] + bhh[n];
#pragma unroll
      for (int mt = 0; mt < 4; mt++) {
        int rbase = wr * 64 + mt * 16 + q * 4;   // = tl (step-local index)
#pragma unroll
        for (int r = 0; r < 4; r++)
          xo[(size_t)(rbase + r) * 512 + n] = f2bf(acc[mt][nt][r] + bias);
      }
    }
    return;
  }

  // --------------------------- lstm part (r7 core) -------------------------
  if (!do_lstm) return;
  const int wg = blockIdx.x & 7, dir = blockIdx.x >> 3;
  const int hc = 16 * wv + l15;
  const u16* XPC = (lc & 1) ? xpc1 : xpc0;

  const u16* Wp = dir ? WHH1 : WHH0;
  bf16x8 wf[4][4];
#pragma unroll
  for (int gi = 0; gi < 4; gi++)
#pragma unroll
    for (int kt = 0; kt < 4; kt++)
      wf[gi][kt] = *(const bf16x8*)&Wp[(gi * 128 + hc) * 128 + kt * 32 + q * 8];

  u16* hb = (u16*)smem;  // [2][16*136]

  float cst[4];
  if (lc == 0) {
    for (int i = tid; i < 16 * 136; i += 512) hb[i] = 0;
#pragma unroll
    for (int r = 0; r < 4; r++) cst[r] = 0.f;
  } else {
#pragma unroll
    for (int r = 0; r < 4; r++) {
      int row = q * 4 + r;
      int g = (dir * 128 + wg * 16 + row) * 128 + hc;
      hb[row * 136 + hc] = HS[g];
      cst[r] = CS[g];
    }
  }

  const u16* xpp = XPC + ((size_t)(dir * 128 + wg * 16) * TC) * 512;
  float xpv[16];
#pragma unroll
  for (int gi = 0; gi < 4; gi++)
#pragma unroll
    for (int r = 0; r < 4; r++)
      xpv[gi * 4 + r] = bf2f(xpp[((size_t)(q * 4 + r) * TC) * 512 + gi * 128 + hc]);

  const int t0 = dir ? (NT - 1 - lc * TC) : (lc * TC);
  const int tstep = dir ? -256 : 256;
  u16* optr[4];
  if (LL == 0) {
#pragma unroll
    for (int r = 0; r < 4; r++)
      optr[r] = OUT + ((size_t)(wg * 16 + q * 4 + r) * NT + t0) * 256 + dir * 128 + hc;
  }

  __syncthreads();

  int p = 0;
  for (int sl = 0; sl < TC; sl++) {
    bf16x8 ah[4];
#pragma unroll
    for (int kt = 0; kt < 4; kt++)
      ah[kt] = *(const bf16x8*)&hb[p * 2176 + l15 * 136 + kt * 32 + q * 8];

    const int sln = (sl + 1 < TC) ? sl + 1 : sl;
    float xnv[16];
#pragma unroll
    for (int gi = 0; gi < 4; gi++)
#pragma unroll
      for (int r = 0; r < 4; r++)
        xnv[gi * 4 + r] = bf2f(xpp[((size_t)(q * 4 + r) * TC + sln) * 512 + gi * 128 + hc]);

    f32x4 acc[4];
#pragma unroll
    for (int gi = 0; gi < 4; gi++)
#pragma unroll
      for (int r = 0; r < 4; r++)
        acc[gi][r] = xpv[gi * 4 + r];
#pragma unroll
    for (int gi = 0; gi < 4; gi++)
#pragma unroll
      for (int kt = 0; kt < 4; kt++)
        acc[gi] = __builtin_amdgcn_mfma_f32_16x16x32_bf16(ah[kt], wf[gi][kt], acc[gi], 0, 0, 0);

#pragma unroll
    for (int r = 0; r < 4; r++) {
      float ei = fast_exp2(L2E * acc[0][r]);
      float ef = fast_exp2(L2E * acc[1][r]);
      float eg = fast_exp2(L2E2 * acc[2][r]);
      float eo = fast_exp2(L2E * acc[3][r]);
      float A = 1.f + ef, B = 1.f + ei, Cg = 1.f + eg;
      float BC = B * Cg;
      float num = cst[r] * ef * BC + ei * (eg - 1.f) * A;
      float cn = num * fast_rcp(A * BC);
      cst[r] = cn;
      float ec = fast_exp2(L2E2 * cn);
      float hv = eo * (ec - 1.f) * fast_rcp((1.f + eo) * (1.f + ec));
      u16 hbv = f2bf(hv);
      int row = q * 4 + r;
      hb[(p ^ 1) * 2176 + row * 136 + hc] = hbv;
      if (LL == 0) {
        *optr[r] = hbv;
        optr[r] += tstep;
      }
      if (sl == TC - 1) {
        int g = (dir * 128 + wg * 16 + row) * 128 + hc;
        HS[g] = hbv;
        CS[g] = cst[r];
        if (LL == 1 && lc == NCHUNK - 1)
          FINALS[(wg * 16 + row) * 256 + dir * 128 + hc] = hv;
      }
    }
    __syncthreads();
    p ^= 1;
#pragma unroll
    for (int i = 0; i < 16; i++) xpv[i] = xnv[i];
  }
}

// ---------------------------------------------------------------------------
// fc: out[b][c] = finals[b][:] . fc_w[c][:] + fc_b[c]  (all f32)
__global__ void fc_kernel(const float* __restrict__ finals, const float* __restrict__ fcw,
                          const float* __restrict__ fcb, float* __restrict__ out) {
  int tid = threadIdx.x;  // 256 = 128 b x 2 c
  int b = tid >> 1, cc = tid & 1;
  float s = fcb[cc];
  for (int k = 0; k < 256; k++) s += finals[b * 256 + k] * fcw[cc * 256 + k];
  out[b * 2 + cc] = s;
}

// ---------------------------------------------------------------------------
extern "C" void kernel_launch(void* const* d_in, const int* in_sizes, int n_in,
                              void* d_out, int out_size, void* d_ws, size_t ws_size,
                              hipStream_t stream) {
  const int*   x        = (const int*)d_in[0];
  const float* emb      = (const float*)d_in[1];
  const float* w_ih_l0  = (const float*)d_in[2];
  const float* w_hh_l0  = (const float*)d_in[3];
  const float* b_ih_l0  = (const float*)d_in[4];
  const float* b_hh_l0  = (const float*)d_in[5];
  const float* w_ih_l0r = (const float*)d_in[6];
  const float* w_hh_l0r = (const float*)d_in[7];
  const float* b_ih_l0r = (const float*)d_in[8];
  const float* b_hh_l0r = (const float*)d_in[9];
  const float* w_ih_l1  = (const float*)d_in[10];
  const float* w_hh_l1  = (const float*)d_in[11];
  const float* b_ih_l1  = (const float*)d_in[12];
  const float* b_hh_l1  = (const float*)d_in[13];
  const float* w_ih_l1r = (const float*)d_in[14];
  const float* w_hh_l1r = (const float*)d_in[15];
  const float* b_ih_l1r = (const float*)d_in[16];
  const float* b_hh_l1r = (const float*)d_in[17];
  const float* fc_w     = (const float*)d_in[18];
  const float* fc_b     = (const float*)d_in[19];
  float* out = (float*)d_out;

  // workspace layout — total 135,856,128 B (exact r2 footprint, proven to run)
  char* ws = (char*)d_ws;
  size_t off = 0;
  u16*   h1cat = (u16*)(ws + off);   off += 67108864;  // [NM][256] bf16
  u16*   xpc0  = (u16*)(ws + off);   off += 33554432;  // xp double buffer 0
  u16*   xpc1  = (u16*)(ws + off);   off += 33554432;  // xp double buffer 1
  u16*   w0pad = (u16*)(ws + off);   off += 262144;    // [2][512][128] bf16
  u16*   wih1b = (u16*)(ws + off);   off += 524288;    // [2][512][256] bf16
  u16*   whhb  = (u16*)(ws + off);   off += 524288;    // [4][512][128] bf16
  u16*   hs    = (u16*)(ws + off);   off += 65536;     // [2][128][128] bf16
  float* cs    = (float*)(ws + off); off += 131072;    // [2][128][128] f32
  float* fin   = (float*)(ws + off); off += 131072;    // [128][256] f32
  if (ws_size < off) return;  // constant across calls -> same work every call

  hipLaunchKernelGGL(padw_kernel, dim3(512), dim3(256), 0, stream,
                     w_ih_l0, w_ih_l0r, w0pad);
  hipLaunchKernelGGL(cvt6_kernel, dim3(512, 6), dim3(256), 0, stream,
                     w_hh_l0, w_hh_l0r, w_hh_l1, w_hh_l1r, w_ih_l1, w_ih_l1r,
                     whhb, whhb + 65536, whhb + 131072, whhb + 196608,
                     wih1b, wih1b + 131072,
                     65536, 65536, 65536, 65536, 131072, 131072);

  // Layer 0: launch k does proj0(k) [k<8] fused with lstm0(k-1) [k>0]
  for (int k = 0; k <= NCHUNK; k++) {
    int do_proj = (k < NCHUNK);
    int do_lstm = (k > 0);
    hipLaunchKernelGGL((fused_chunk<128, 0>), dim3(do_proj ? 1040 : 16), dim3(512), 0, stream,
                       do_lstm, k - 1, k,
                       emb, (const u16*)nullptr, x, w0pad, w0pad + 65536,
                       b_ih_l0, b_hh_l0, b_ih_l0r, b_hh_l0r,
                       xpc0, xpc1, whhb, whhb + 65536,
                       h1cat, fin, hs, cs);
  }
  // Layer 1: same pattern, proj reads h1cat (complete after layer-0 phase)
  for (int k = 0; k <= NCHUNK; k++) {
    int do_proj = (k < NCHUNK);
    int do_lstm = (k > 0);
    hipLaunchKernelGGL((fused_chunk<256, 1>), dim3(do_proj ? 1040 : 16), dim3(512), 0, stream,
                       do_lstm, k - 1, k,
                       (const float*)nullptr, h1cat, (const int*)nullptr,
                       wih1b, wih1b + 131072,
                       b_ih_l1, b_hh_l1, b_ih_l1r, b_hh_l1r,
                       xpc0, xpc1, whhb + 131072, whhb + 196608,
                       h1cat, fin, hs, cs);
  }
  hipLaunchKernelGGL(fc_kernel, dim3(1), dim3(256), 0, stream, fin, fc_w, fc_b, out);
}

// Round 9
// 2188.756 us; speedup vs baseline: 1.5363x; 1.0157x over previous
//
#include <hip/hip_runtime.h>
#include <hip/hip_bf16.h>
#include <stdint.h>

// ---------------------------------------------------------------------------
// BiLSTM classifier: V=50000 E=100 H=128 B=128 T=1024 C=2. f32 I/O.
// Round 9 = r8 fused structure + lstm issue cuts:
//   * xpc step-contiguous tiles [dir*8+wg][sl][16 rows][512] -> lstm xp via
//     1 base ptr + 16 imm-offset loads (+16KB bump/step); proj epilogue
//     keeps r5-style 16-lane x 32B coalesced stores.
//   * L2E/L2E2 folded into weight+bias conversion (gate-dependent row scale)
//     -> gate exp2 args come straight from MFMA acc.
//   * step loop unrolled x2 with alternating prefetch reg sets.
// ---------------------------------------------------------------------------

typedef unsigned short u16;
typedef short bf16x8 __attribute__((ext_vector_type(8)));
typedef unsigned short ushort8v __attribute__((ext_vector_type(8)));
typedef float f32x4 __attribute__((ext_vector_type(4)));

#define NB 128
#define NT 1024
#define NH 128
#define NM (NB * NT)   // 131072
#define TC 128         // chunk length (steps)
#define NCHUNK (NT / TC)

#define L2E  1.44269504088896f
#define L2E2 2.88539008177793f

__device__ __forceinline__ u16 f2bf(float f) {
  union { float f; unsigned int i; } v; v.f = f;
  unsigned int i = v.i;
  return (u16)((i + 0x7FFFu + ((i >> 16) & 1u)) >> 16);  // RNE
}
__device__ __forceinline__ float bf2f(u16 u) {
  union { unsigned int i; float f; } v; v.i = ((unsigned int)u) << 16; return v.f;
}

#if __has_builtin(__builtin_amdgcn_exp2f)
__device__ __forceinline__ float fast_exp2(float x) { return __builtin_amdgcn_exp2f(x); }
#else
__device__ __forceinline__ float fast_exp2(float x) { return exp2f(x); }
#endif
#if __has_builtin(__builtin_amdgcn_rcpf)
__device__ __forceinline__ float fast_rcp(float x) { return __builtin_amdgcn_rcpf(x); }
#else
__device__ __forceinline__ float fast_rcp(float x) { return 1.0f / x; }
#endif

// ---------------------------------------------------------------------------
// pad w_ih_l0 f32 [512,100] -> bf16 [2][512][128], rows scaled by gate factor
__global__ void padw_kernel(const float* __restrict__ w0, const float* __restrict__ w1,
                            u16* __restrict__ out) {
  int idx = blockIdx.x * 256 + threadIdx.x;  // 131072
  int d = idx >> 16;
  int n = (idx >> 7) & 511;
  int k = idx & 127;
  float sc = ((n >> 7) == 2) ? L2E2 : L2E;
  const float* w = d ? w1 : w0;
  out[idx] = (k < 100) ? f2bf(w[n * 100 + k] * sc) : (u16)0;
}

// fused f32->bf16 convert for 6 weight arrays, rows scaled by gate factor.
// gs: idx>>gs gives gate (0..3); w_hh [512][128] -> gs=14, w_ih_l1 [512][256]
// -> gs=15.
__global__ void cvt6_kernel(const float* s0, const float* s1, const float* s2,
                            const float* s3, const float* s4, const float* s5,
                            u16* d0, u16* d1, u16* d2, u16* d3, u16* d4, u16* d5,
                            int n0, int n1, int n2, int n3, int n4, int n5) {
  int y = blockIdx.y;
  const float* s; u16* d; int n; int gs;
  switch (y) {
    case 0: s = s0; d = d0; n = n0; gs = 14; break;
    case 1: s = s1; d = d1; n = n1; gs = 14; break;
    case 2: s = s2; d = d2; n = n2; gs = 14; break;
    case 3: s = s3; d = d3; n = n3; gs = 14; break;
    case 4: s = s4; d = d4; n = n4; gs = 15; break;
    default: s = s5; d = d5; n = n5; gs = 15; break;
  }
  int i = blockIdx.x * 256 + threadIdx.x;
  if (i < n) {
    float sc = (((i >> gs) & 3) == 2) ? L2E2 : L2E;
    d[i] = f2bf(s[i] * sc);
  }
}

// ---------------------------------------------------------------------------
// Fused kernel. Blocks 0..15: lstm chunk `lc` (if do_lstm). Blocks 16..1039:
// proj chunk `pc` (grid sized to 16 when do_proj==0).
// xpc layout: [dir*8+wg][sl][rowb(16)][512] bf16 (step-contiguous 16KB tiles).
template <int PK, int LL>
__global__ __launch_bounds__(512) void fused_chunk(
    int do_lstm, int lc, int pc,
    const float* __restrict__ Aemb, const u16* __restrict__ Ah,
    const int* __restrict__ X,
    const u16* __restrict__ W0, const u16* __restrict__ W1,   // [512][PK] bf16
    const float* __restrict__ bih0, const float* __restrict__ bhh0,
    const float* __restrict__ bih1, const float* __restrict__ bhh1,
    u16* __restrict__ xpc0, u16* __restrict__ xpc1,           // double buffer
    const u16* __restrict__ WHH0, const u16* __restrict__ WHH1,
    u16* __restrict__ OUT, float* __restrict__ FINALS,
    u16* __restrict__ HS, float* __restrict__ CS)
{
  // shared memory union: proj As(18432)+Bs(18432)+toks(512); lstm hb(8704)
  __shared__ __align__(16) unsigned char smem[37888];

  const int tid = threadIdx.x;
  const int lane = tid & 63, wv = tid >> 6;
  const int l15 = lane & 15, q = lane >> 4;

  if (blockIdx.x >= 16) {
    // ------------------------- proj part (8 waves, 64x32 wave tiles) -------
    constexpr int BK = 64;
    constexpr int LDA = 72;
    constexpr bool GATHER = (PK == 128);
    u16* As = (u16*)smem;
    u16* Bs = As + 128 * LDA;
    int* toks = (int*)(Bs + 128 * LDA);

    const int pb = blockIdx.x - 16;
    const int b = pb & 127;
    const int gate = (pb >> 7) & 3;
    const int nt0 = gate * 128;
    const int dir = pb >> 9;
    const u16* W = dir ? W1 : W0;
    u16* XPC = (pc & 1) ? xpc1 : xpc0;

    const int wr = wv >> 2, wc = wv & 3;   // 2 x 4 waves

    if (GATHER) {
      if (tid < 128) {
        int t = dir ? (NT - 1 - pc * TC - tid) : (pc * TC + tid);
        toks[tid] = X[b * NT + t];
      }
    }

    f32x4 acc[4][2];
#pragma unroll
    for (int a = 0; a < 4; a++)
#pragma unroll
      for (int bb = 0; bb < 2; bb++)
        acc[a][bb] = (f32x4){0.f, 0.f, 0.f, 0.f};

    const int srow = tid >> 3;        // 0..63
    const int sseg = (tid & 7) * 8;   // 0..56

    for (int k0 = 0; k0 < PK; k0 += BK) {
      __syncthreads();   // also covers toks on first iteration
#pragma unroll
      for (int p = 0; p < 2; p++) {
        int row = srow + p * 64;
        if (GATHER) {
          int tok = toks[row];
          const float* er = Aemb + (size_t)tok * 100;
          int kb = k0 + sseg;
          union { ushort8v v; u16 e[8]; } tu;
          if (kb + 8 <= 100) {
            f32x4 a0 = *(const f32x4*)&er[kb];
            f32x4 a1 = *(const f32x4*)&er[kb + 4];
#pragma unroll
            for (int j = 0; j < 4; j++) { tu.e[j] = f2bf(a0[j]); tu.e[4 + j] = f2bf(a1[j]); }
          } else {
#pragma unroll
            for (int j = 0; j < 8; j++) tu.e[j] = (kb + j < 100) ? f2bf(er[kb + j]) : (u16)0;
          }
          *(ushort8v*)&As[row * LDA + sseg] = tu.v;
        } else {
          int t = dir ? (NT - 1 - pc * TC - row) : (pc * TC + row);
          const u16* srcA = Ah + (size_t)(b * NT + t) * PK + k0 + sseg;
          *(ushort8v*)&As[row * LDA + sseg] = *(const ushort8v*)srcA;
        }
        const u16* srcB = W + (size_t)(nt0 + row) * PK + k0 + sseg;
        *(ushort8v*)&Bs[row * LDA + sseg] = *(const ushort8v*)srcB;
      }
      __syncthreads();
#pragma unroll
      for (int kk = 0; kk < BK; kk += 32) {
        bf16x8 af[4], bfr[2];
#pragma unroll
        for (int mt = 0; mt < 4; mt++)
          af[mt] = *(const bf16x8*)&As[(wr * 64 + mt * 16 + l15) * LDA + kk + q * 8];
#pragma unroll
        for (int nt = 0; nt < 2; nt++)
          bfr[nt] = *(const bf16x8*)&Bs[(wc * 32 + nt * 16 + l15) * LDA + kk + q * 8];
#pragma unroll
        for (int mt = 0; mt < 4; mt++)
#pragma unroll
          for (int nt = 0; nt < 2; nt++)
            acc[mt][nt] = __builtin_amdgcn_mfma_f32_16x16x32_bf16(af[mt], bfr[nt], acc[mt][nt], 0, 0, 0);
      }
    }

    const float* bih = dir ? bih1 : bih0;
    const float* bhh = dir ? bhh1 : bhh0;
    const float gsc = (gate == 2) ? L2E2 : L2E;
    // step-contiguous tile base for (dir, wg=b>>4), row rowb=b&15
    u16* xo = XPC + (size_t)(dir * 8 + (b >> 4)) * TC * 8192 + (size_t)(b & 15) * 512;
#pragma unroll
    for (int nt = 0; nt < 2; nt++) {
      int n = nt0 + wc * 32 + nt * 16 + l15;
      float bias = (bih[n] + bhh[n]) * gsc;
#pragma unroll
      for (int mt = 0; mt < 4; mt++) {
        int slb = wr * 64 + mt * 16 + q * 4;   // step-local index base
#pragma unroll
        for (int r = 0; r < 4; r++)
          xo[(size_t)(slb + r) * 8192 + n] = f2bf(acc[mt][nt][r] + bias);
      }
    }
    return;
  }

  // --------------------------- lstm part -----------------------------------
  if (!do_lstm) return;
  const int wg = blockIdx.x & 7, dir = blockIdx.x >> 3;
  const int hc = 16 * wv + l15;
  const u16* XPC = (lc & 1) ? xpc1 : xpc0;

  const u16* Wp = dir ? WHH1 : WHH0;
  bf16x8 wf[4][4];
#pragma unroll
  for (int gi = 0; gi < 4; gi++)
#pragma unroll
    for (int kt = 0; kt < 4; kt++)
      wf[gi][kt] = *(const bf16x8*)&Wp[(gi * 128 + hc) * 128 + kt * 32 + q * 8];

  u16* hb = (u16*)smem;  // [2][16*136]

  float cst[4];
  if (lc == 0) {
    for (int i = tid; i < 16 * 136; i += 512) hb[i] = 0;
#pragma unroll
    for (int r = 0; r < 4; r++) cst[r] = 0.f;
  } else {
#pragma unroll
    for (int r = 0; r < 4; r++) {
      int row = q * 4 + r;
      int g = (dir * 128 + wg * 16 + row) * 128 + hc;
      hb[row * 136 + hc] = HS[g];
      cst[r] = CS[g];
    }
  }

  // lane base into step-contiguous tiles: + row-base (q*4)*512 + col hc
  const u16* xb = XPC + (size_t)(dir * 8 + wg) * TC * 8192 + (q * 4) * 512 + hc;

  // xp regs: [r*4+gi] ; two alternating sets for unroll-2
  float xA[16], xB[16];
#pragma unroll
  for (int r = 0; r < 4; r++)
#pragma unroll
    for (int gi = 0; gi < 4; gi++)
      xA[r * 4 + gi] = bf2f(xb[r * 512 + gi * 128]);

  const int t0 = dir ? (NT - 1 - lc * TC) : (lc * TC);
  const int tstep = dir ? -256 : 256;
  u16* optr[4];
  if (LL == 0) {
#pragma unroll
    for (int r = 0; r < 4; r++)
      optr[r] = OUT + ((size_t)(wg * 16 + q * 4 + r) * NT + t0) * 256 + dir * 128 + hc;
  }

  __syncthreads();

  int p = 0;
#pragma unroll 1
  for (int sl = 0; sl < TC; sl += 2) {
#pragma unroll
    for (int half = 0; half < 2; half++) {
      const int scur = sl + half;
      float* xcur = half ? xB : xA;
      float* xnxt = half ? xA : xB;

      bf16x8 ah[4];
#pragma unroll
      for (int kt = 0; kt < 4; kt++)
        ah[kt] = *(const bf16x8*)&hb[p * 2176 + l15 * 136 + kt * 32 + q * 8];

      // prefetch step scur+1 (clamped: harmless re-read at the end)
      {
        const int sn = (scur + 1 < TC) ? scur + 1 : scur;
        const u16* nb = xb + (size_t)sn * 8192;
#pragma unroll
        for (int r = 0; r < 4; r++)
#pragma unroll
          for (int gi = 0; gi < 4; gi++)
            xnxt[r * 4 + gi] = bf2f(nb[r * 512 + gi * 128]);
      }

      f32x4 acc[4];
#pragma unroll
      for (int gi = 0; gi < 4; gi++)
#pragma unroll
        for (int r = 0; r < 4; r++)
          acc[gi][r] = xcur[r * 4 + gi];
#pragma unroll
      for (int gi = 0; gi < 4; gi++)
#pragma unroll
        for (int kt = 0; kt < 4; kt++)
          acc[gi] = __builtin_amdgcn_mfma_f32_16x16x32_bf16(ah[kt], wf[gi][kt], acc[gi], 0, 0, 0);

#pragma unroll
      for (int r = 0; r < 4; r++) {
        // preacts pre-scaled by L2E (i,f,o) / L2E2 (g) via weight folding
        float ei = fast_exp2(acc[0][r]);
        float ef = fast_exp2(acc[1][r]);
        float eg = fast_exp2(acc[2][r]);
        float eo = fast_exp2(acc[3][r]);
        float A = 1.f + ef, B = 1.f + ei, Cg = 1.f + eg;
        float BC = B * Cg;
        float num = cst[r] * ef * BC + ei * (eg - 1.f) * A;
        float cn = num * fast_rcp(A * BC);
        cst[r] = cn;
        float ec = fast_exp2(L2E2 * cn);
        float hv = eo * (ec - 1.f) * fast_rcp((1.f + eo) * (1.f + ec));
        u16 hbv = f2bf(hv);
        int row = q * 4 + r;
        hb[(p ^ 1) * 2176 + row * 136 + hc] = hbv;
        if (LL == 0) {
          *optr[r] = hbv;
          optr[r] += tstep;
        }
        if (scur == TC - 1) {
          int g = (dir * 128 + wg * 16 + row) * 128 + hc;
          HS[g] = hbv;
          CS[g] = cst[r];
          if (LL == 1 && lc == NCHUNK - 1)
            FINALS[(wg * 16 + row) * 256 + dir * 128 + hc] = hv;
        }
      }
      __syncthreads();
      p ^= 1;
    }
  }
}

// ---------------------------------------------------------------------------
// fc: out[b][c] = finals[b][:] . fc_w[c][:] + fc_b[c]  (all f32)
__global__ void fc_kernel(const float* __restrict__ finals, const float* __restrict__ fcw,
                          const float* __restrict__ fcb, float* __restrict__ out) {
  int tid = threadIdx.x;  // 256 = 128 b x 2 c
  int b = tid >> 1, cc = tid & 1;
  float s = fcb[cc];
  for (int k = 0; k < 256; k++) s += finals[b * 256 + k] * fcw[cc * 256 + k];
  out[b * 2 + cc] = s;
}

// ---------------------------------------------------------------------------
extern "C" void kernel_launch(void* const* d_in, const int* in_sizes, int n_in,
                              void* d_out, int out_size, void* d_ws, size_t ws_size,
                              hipStream_t stream) {
  const int*   x        = (const int*)d_in[0];
  const float* emb      = (const float*)d_in[1];
  const float* w_ih_l0  = (const float*)d_in[2];
  const float* w_hh_l0  = (const float*)d_in[3];
  const float* b_ih_l0  = (const float*)d_in[4];
  const float* b_hh_l0  = (const float*)d_in[5];
  const float* w_ih_l0r = (const float*)d_in[6];
  const float* w_hh_l0r = (const float*)d_in[7];
  const float* b_ih_l0r = (const float*)d_in[8];
  const float* b_hh_l0r = (const float*)d_in[9];
  const float* w_ih_l1  = (const float*)d_in[10];
  const float* w_hh_l1  = (const float*)d_in[11];
  const float* b_ih_l1  = (const float*)d_in[12];
  const float* b_hh_l1  = (const float*)d_in[13];
  const float* w_ih_l1r = (const float*)d_in[14];
  const float* w_hh_l1r = (const float*)d_in[15];
  const float* b_ih_l1r = (const float*)d_in[16];
  const float* b_hh_l1r = (const float*)d_in[17];
  const float* fc_w     = (const float*)d_in[18];
  const float* fc_b     = (const float*)d_in[19];
  float* out = (float*)d_out;

  // workspace layout — total 135,856,128 B (r8 footprint, proven to run)
  char* ws = (char*)d_ws;
  size_t off = 0;
  u16*   h1cat = (u16*)(ws + off);   off += 67108864;  // [NM][256] bf16
  u16*   xpc0  = (u16*)(ws + off);   off += 33554432;  // xp double buffer 0
  u16*   xpc1  = (u16*)(ws + off);   off += 33554432;  // xp double buffer 1
  u16*   w0pad = (u16*)(ws + off);   off += 262144;    // [2][512][128] bf16 (scaled)
  u16*   wih1b = (u16*)(ws + off);   off += 524288;    // [2][512][256] bf16 (scaled)
  u16*   whhb  = (u16*)(ws + off);   off += 524288;    // [4][512][128] bf16 (scaled)
  u16*   hs    = (u16*)(ws + off);   off += 65536;     // [2][128][128] bf16
  float* cs    = (float*)(ws + off); off += 131072;    // [2][128][128] f32
  float* fin   = (float*)(ws + off); off += 131072;    // [128][256] f32
  if (ws_size < off) return;  // constant across calls -> same work every call

  hipLaunchKernelGGL(padw_kernel, dim3(512), dim3(256), 0, stream,
                     w_ih_l0, w_ih_l0r, w0pad);
  hipLaunchKernelGGL(cvt6_kernel, dim3(512, 6), dim3(256), 0, stream,
                     w_hh_l0, w_hh_l0r, w_hh_l1, w_hh_l1r, w_ih_l1, w_ih_l1r,
                     whhb, whhb + 65536, whhb + 131072, whhb + 196608,
                     wih1b, wih1b + 131072,
                     65536, 65536, 65536, 65536, 131072, 131072);

  // Layer 0: launch k does proj0(k) [k<8] fused with lstm0(k-1) [k>0]
  for (int k = 0; k <= NCHUNK; k++) {
    int do_proj = (k < NCHUNK);
    int do_lstm = (k > 0);
    hipLaunchKernelGGL((fused_chunk<128, 0>), dim3(do_proj ? 1040 : 16), dim3(512), 0, stream,
                       do_lstm, k - 1, k,
                       emb, (const u16*)nullptr, x, w0pad, w0pad + 65536,
                       b_ih_l0, b_hh_l0, b_ih_l0r, b_hh_l0r,
                       xpc0, xpc1, whhb, whhb + 65536,
                       h1cat, fin, hs, cs);
  }
  // Layer 1: same pattern, proj reads h1cat (complete after layer-0 phase)
  for (int k = 0; k <= NCHUNK; k++) {
    int do_proj = (k < NCHUNK);
    int do_lstm = (k > 0);
    hipLaunchKernelGGL((fused_chunk<256, 1>), dim3(do_proj ? 1040 : 16), dim3(512), 0, stream,
                       do_lstm, k - 1, k,
                       (const float*)nullptr, h1cat, (const int*)nullptr,
                       wih1b, wih1b + 131072,
                       b_ih_l1, b_hh_l1, b_ih_l1r, b_hh_l1r,
                       xpc0, xpc1, whhb + 131072, whhb + 196608,
                       h1cat, fin, hs, cs);
  }
  hipLaunchKernelGGL(fc_kernel, dim3(1), dim3(256), 0, stream, fin, fc_w, fc_b, out);
}